// Round 13
// baseline (229.401 us; speedup 1.0000x reference)
//
#include <hip/hip_runtime.h>

#define M_VERT 32768
#define NBATCH 8
#define FIN 32
#define RANK 5
#define FILT 32
#define E_NNZ 262144
#define ROWLEN 256                    // NBATCH*FIN elements per vertex row
#define EVROW 40                      // fixed ev slots per row (P(cnt>40) ~ 1e-16), mult of 8

typedef short short8 __attribute__((ext_vector_type(8)));
typedef float f32x4 __attribute__((ext_vector_type(4)));
typedef unsigned long long u64;

__device__ __forceinline__ float bfl(unsigned int u) {           // low bf16 -> f32
    unsigned int x = u << 16; return __builtin_bit_cast(float, x);
}
__device__ __forceinline__ float bfh(unsigned int u) {           // high bf16 -> f32
    unsigned int x = u & 0xffff0000u; return __builtin_bit_cast(float, x);
}
__device__ __forceinline__ unsigned int f2bf(float f) {          // f32 -> bf16 (RNE)
    unsigned int x = __builtin_bit_cast(unsigned int, f);
    return (x + 0x7fffu + ((x >> 16) & 1u)) >> 16;
}
__device__ __forceinline__ unsigned int pk(float a, float b) {
    return f2bf(a) | (f2bf(b) << 16);
}

// ---------------- pack x -> T0 bf16 + CSR build + packw (R6/R10-proven) ----------------

__global__ void pack_kernel(const float* __restrict__ x, unsigned short* __restrict__ T0,
                            const int* __restrict__ rows, const int* __restrict__ cols,
                            const float* __restrict__ vals,
                            int* __restrict__ fill, int2* __restrict__ ev,
                            const float* __restrict__ W, unsigned short* __restrict__ Wb) {
    int tid = blockIdx.x * blockDim.x + threadIdx.x;   // M*32 threads
    int m = tid >> 5;
    int r = tid & 31;
    int n = r >> 2;
    int q = r & 3;
    const float* src = x + ((size_t)n * M_VERT + m) * FIN + q * 8;
    float4 v0 = *(const float4*)(src);
    float4 v1 = *(const float4*)(src + 4);
    uint4 u;
    u.x = pk(v0.x, v0.y); u.y = pk(v0.z, v0.w);
    u.z = pk(v1.x, v1.y); u.w = pk(v1.z, v1.w);
    *(uint4*)(T0 + (size_t)m * ROWLEN + n * FIN + q * 8) = u;

    if (tid < E_NNZ) {
        int rr = rows[tid];
        int pos = atomicAdd(&fill[rr], 1);
        if (pos < EVROW) {                       // safety clamp (never taken in practice)
            int2 p; p.x = cols[tid]; p.y = __builtin_bit_cast(int, vals[tid]);
            ev[rr * EVROW + pos] = p;
        }
    }

    if (tid < 640) {
        int lane = tid & 63;
        int kf = tid >> 6;
        int k = kf >> 1, ft = kf & 1;
        int f = ft * 16 + (lane & 15);
        int fin0 = (lane >> 4) * 8;
        unsigned short tmp[8];
#pragma unroll
        for (int j = 0; j < 8; ++j)
            tmp[j] = (unsigned short)f2bf(W[((fin0 + j) * RANK + k) * FILT + f]);
        uint4 uw;
        uw.x = (unsigned int)tmp[0] | ((unsigned int)tmp[1] << 16);
        uw.y = (unsigned int)tmp[2] | ((unsigned int)tmp[3] << 16);
        uw.z = (unsigned int)tmp[4] | ((unsigned int)tmp[5] << 16);
        uw.w = (unsigned int)tmp[6] | ((unsigned int)tmp[7] << 16);
        *(uint4*)(Wb + (size_t)tid * 8) = uw;
    }
}

// ---------------- SpMM (bf16): Tout = L*Tin  or  2*L*Tin - Tsub ----------------
// One wave per vertex; uniform bounds via readfirstlane -> scalar ev loads; 64
// lanes gather the SAME row -> one coalesced 512B transaction per edge; 8
// outstanding gathers. Masked tail -> no ev memset.
// R12: Tout store is NON-TEMPORAL. The cached write was write-allocating
// 16.8 MB into L2 per dispatch, evicting the Tin lines the 134 MB gather demand
// reuses (the R2-proven pollution mechanism). Successor warm-start loss is small
// (random gathers see <=25% warm lines either way). Tsub stays nt (pure stream).

__global__ __launch_bounds__(256) void spmm_kernel(const int* __restrict__ cnt,
                                                   const u64* __restrict__ ev,
                                                   const unsigned short* __restrict__ Tin,
                                                   const unsigned short* __restrict__ Tsub,
                                                   unsigned short* __restrict__ Tout, int cheb) {
    int w = threadIdx.x >> 6;
    int l = threadIdx.x & 63;
    int m = blockIdx.x * 4 + w;
    unsigned int coff = (unsigned int)l * 8u;    // byte offset within 512B row
    int c = __builtin_amdgcn_readfirstlane(cnt[m]);
    if (c > EVROW) c = EVROW;                    // matches scatter clamp
    int s = m * EVROW;
    int cf = c & ~7;
    const char* tb = (const char*)Tin;
    float a0 = 0.f, a1 = 0.f, a2 = 0.f, a3 = 0.f;
    int j = 0;
    for (; j < cf; j += 8) {                     // full 8-packs (no predication)
        u64 ed[8];
#pragma unroll
        for (int i = 0; i < 8; ++i) ed[i] = ev[s + j + i];   // uniform -> scalar loads
        uint2 t[8];
#pragma unroll
        for (int i = 0; i < 8; ++i)
            t[i] = *(const uint2*)(tb + (((unsigned int)ed[i]) << 9) + coff);
#pragma unroll
        for (int i = 0; i < 8; ++i) {
            float v = __builtin_bit_cast(float, (unsigned int)(ed[i] >> 32));
            a0 += v * bfl(t[i].x); a1 += v * bfh(t[i].x);
            a2 += v * bfl(t[i].y); a3 += v * bfh(t[i].y);
        }
    }
    if (j < c) {                                 // masked tail (1..7 real edges)
        int rem = c - j;
        u64 ed[8];
#pragma unroll
        for (int i = 0; i < 8; ++i) ed[i] = ev[s + j + i];   // may read garbage pads
        unsigned int cm[8]; float vm[8];
#pragma unroll
        for (int i = 0; i < 8; ++i) {            // mask BEFORE any deref
            bool ok = i < rem;
            cm[i] = ok ? (unsigned int)ed[i] : 0u;
            vm[i] = ok ? __builtin_bit_cast(float, (unsigned int)(ed[i] >> 32)) : 0.f;
        }
        uint2 t[8];
#pragma unroll
        for (int i = 0; i < 8; ++i)
            t[i] = *(const uint2*)(tb + (cm[i] << 9) + coff);
#pragma unroll
        for (int i = 0; i < 8; ++i) {
            a0 += vm[i] * bfl(t[i].x); a1 += vm[i] * bfh(t[i].x);
            a2 += vm[i] * bfl(t[i].y); a3 += vm[i] * bfh(t[i].y);
        }
    }
    size_t moff = (size_t)m * 512 + coff;
    if (cheb) {
        u64 o = __builtin_nontemporal_load((const u64*)((const char*)Tsub + moff));
        unsigned int ox = (unsigned int)o, oy = (unsigned int)(o >> 32);
        a0 = 2.f * a0 - bfl(ox); a1 = 2.f * a1 - bfh(ox);
        a2 = 2.f * a2 - bfl(oy); a3 = 2.f * a3 - bfh(oy);
    }
    u64 rr = (u64)pk(a0, a1) | ((u64)pk(a2, a3) << 32);
    __builtin_nontemporal_store(rr, (u64*)((char*)Tout + moff));
}

// ---------------- fused final SpMM + GEMM (overlapped, R11-proven) ----------------
// Block = 1024 threads (16 waves) owns 64 vertices.
// Phase A: wave w computes T4 rows w*4..+3 = 2*L*T3 - T2 into LDS (swizzled);
// the T2 row it reads is also stashed into sT2 (k=2 never touches global).
// R12: the 6 gemm A-fragments (k in {0,1,3} x 2 tasks) are ISSUED BEFORE
// phase A -- their ~500cy latency hides under the gather loop instead of
// stacking after it (+24 VGPR -> ~56, under the 64 cap of launch_bounds(1024,8)).
// k in {0,1,3} MFMAs run pre-barrier (overlap with stragglers); k=2/k=4 (LDS)
// post-barrier.

__global__ __launch_bounds__(1024, 8) void spmm4_gemm_kernel(
        const int* __restrict__ cnt, const u64* __restrict__ ev,
        const unsigned short* __restrict__ T0, const unsigned short* __restrict__ T1,
        const unsigned short* __restrict__ T2, const unsigned short* __restrict__ T3,
        const unsigned short* __restrict__ Wb, const float* __restrict__ bias,
        float* __restrict__ out) {
    __shared__ unsigned short sT4[64 * 256];     // 32 KB, swizzled
    __shared__ unsigned short sT2[64 * 256];     // 32 KB, swizzled
    int w = threadIdx.x >> 6;                    // wave 0..15
    int l = threadIdx.x & 63;
    int mb0 = blockIdx.x * 64;
    unsigned int coff = (unsigned int)l * 8u;
    const char* tb = (const char*)T3;            // Tin = T3

    // ---- early issue: gemm A-fragments for k in {0,1,3}, both tasks ----
    int lrow = l & 15;           // A's m-offset AND C's column f
    int quad = l >> 4;
    int n   = w & 7;
    int rg0 = w >> 3;
    int rg1 = 2 + rg0;
    int m0l0 = rg0 * 16, m0l1 = rg1 * 16;
    size_t ab0 = (size_t)(mb0 + m0l0 + lrow) * ROWLEN + quad * 8 + n * FIN;
    size_t ab1 = (size_t)(mb0 + m0l1 + lrow) * ROWLEN + quad * 8 + n * FIN;
    short8 a0A = *(const short8*)(T0 + ab0);
    short8 a0B = *(const short8*)(T0 + ab1);
    short8 a1A = *(const short8*)(T1 + ab0);
    short8 a1B = *(const short8*)(T1 + ab1);
    short8 a3A = *(const short8*)(T3 + ab0);
    short8 a3B = *(const short8*)(T3 + ab1);

    // ---- phase A: T4 rows = 2*L*T3 - T2 -> sT4; raw T2 rows -> sT2 ----
    for (int vi = 0; vi < 4; ++vi) {
        int lr = w * 4 + vi;                     // local row 0..63
        int m = mb0 + lr;
        int c = __builtin_amdgcn_readfirstlane(cnt[m]);
        if (c > EVROW) c = EVROW;
        int s = m * EVROW;
        int cf = c & ~7;
        float a0 = 0.f, a1 = 0.f, a2 = 0.f, a3 = 0.f;
        int j = 0;
        for (; j < cf; j += 8) {
            u64 ed[8];
#pragma unroll
            for (int i = 0; i < 8; ++i) ed[i] = ev[s + j + i];
            uint2 t[8];
#pragma unroll
            for (int i = 0; i < 8; ++i)
                t[i] = *(const uint2*)(tb + (((unsigned int)ed[i]) << 9) + coff);
#pragma unroll
            for (int i = 0; i < 8; ++i) {
                float v = __builtin_bit_cast(float, (unsigned int)(ed[i] >> 32));
                a0 += v * bfl(t[i].x); a1 += v * bfh(t[i].x);
                a2 += v * bfl(t[i].y); a3 += v * bfh(t[i].y);
            }
        }
        if (j < c) {
            int rem = c - j;
            u64 ed[8];
#pragma unroll
            for (int i = 0; i < 8; ++i) ed[i] = ev[s + j + i];
            unsigned int cm[8]; float vm[8];
#pragma unroll
            for (int i = 0; i < 8; ++i) {
                bool ok = i < rem;
                cm[i] = ok ? (unsigned int)ed[i] : 0u;
                vm[i] = ok ? __builtin_bit_cast(float, (unsigned int)(ed[i] >> 32)) : 0.f;
            }
            uint2 t[8];
#pragma unroll
            for (int i = 0; i < 8; ++i)
                t[i] = *(const uint2*)(tb + (cm[i] << 9) + coff);
#pragma unroll
            for (int i = 0; i < 8; ++i) {
                a0 += vm[i] * bfl(t[i].x); a1 += vm[i] * bfh(t[i].x);
                a2 += vm[i] * bfl(t[i].y); a3 += vm[i] * bfh(t[i].y);
            }
        }
        size_t moff = (size_t)(mb0 + lr) * 512 + coff;
        u64 o = *(const u64*)((const char*)T2 + moff);        // cached: reused via sT2
        unsigned int ox = (unsigned int)o, oy = (unsigned int)(o >> 32);
        unsigned int swz = coff ^ (((unsigned int)lr & 7u) << 4);
        *(u64*)((char*)sT2 + lr * 512 + swz) = o;             // stash raw T2 row
        a0 = 2.f * a0 - bfl(ox); a1 = 2.f * a1 - bfh(ox);
        a2 = 2.f * a2 - bfl(oy); a3 = 2.f * a3 - bfh(oy);
        uint2 rr;
        rr.x = pk(a0, a1); rr.y = pk(a2, a3);
        *(uint2*)((char*)sT4 + lr * 512 + swz) = rr;
    }

    // ---- phase B (early, pre-barrier): k in {0,1,3} for both tasks ----
    float b0 = bias[lrow];
    float b1 = bias[16 + lrow];

    f32x4 c00 = {0.f, 0.f, 0.f, 0.f};   // task0, filt 0-15
    f32x4 c01 = {0.f, 0.f, 0.f, 0.f};   // task0, filt 16-31
    f32x4 c10 = {0.f, 0.f, 0.f, 0.f};   // task1, filt 0-15
    f32x4 c11 = {0.f, 0.f, 0.f, 0.f};   // task1, filt 16-31

    {
        short8 f00 = *(const short8*)(Wb + ((size_t)0 * 64 + l) * 8);
        short8 f01 = *(const short8*)(Wb + ((size_t)1 * 64 + l) * 8);
        c00 = __builtin_amdgcn_mfma_f32_16x16x32_bf16(a0A, f00, c00, 0, 0, 0);
        c01 = __builtin_amdgcn_mfma_f32_16x16x32_bf16(a0A, f01, c01, 0, 0, 0);
        c10 = __builtin_amdgcn_mfma_f32_16x16x32_bf16(a0B, f00, c10, 0, 0, 0);
        c11 = __builtin_amdgcn_mfma_f32_16x16x32_bf16(a0B, f01, c11, 0, 0, 0);
        short8 f10 = *(const short8*)(Wb + ((size_t)2 * 64 + l) * 8);
        short8 f11 = *(const short8*)(Wb + ((size_t)3 * 64 + l) * 8);
        c00 = __builtin_amdgcn_mfma_f32_16x16x32_bf16(a1A, f10, c00, 0, 0, 0);
        c01 = __builtin_amdgcn_mfma_f32_16x16x32_bf16(a1A, f11, c01, 0, 0, 0);
        c10 = __builtin_amdgcn_mfma_f32_16x16x32_bf16(a1B, f10, c10, 0, 0, 0);
        c11 = __builtin_amdgcn_mfma_f32_16x16x32_bf16(a1B, f11, c11, 0, 0, 0);
        short8 f30 = *(const short8*)(Wb + ((size_t)6 * 64 + l) * 8);
        short8 f31 = *(const short8*)(Wb + ((size_t)7 * 64 + l) * 8);
        c00 = __builtin_amdgcn_mfma_f32_16x16x32_bf16(a3A, f30, c00, 0, 0, 0);
        c01 = __builtin_amdgcn_mfma_f32_16x16x32_bf16(a3A, f31, c01, 0, 0, 0);
        c10 = __builtin_amdgcn_mfma_f32_16x16x32_bf16(a3B, f30, c10, 0, 0, 0);
        c11 = __builtin_amdgcn_mfma_f32_16x16x32_bf16(a3B, f31, c11, 0, 0, 0);
    }

    __syncthreads();

    // ---- phase B (late, post-barrier): k=2 (sT2) and k=4 (sT4) ----
    {
        int rl0 = m0l0 + lrow;
        int rl1 = m0l1 + lrow;
        unsigned int bo0 = ((unsigned int)(n * 64 + quad * 16))
                         ^ (((unsigned int)rl0 & 7u) << 4);
        unsigned int bo1 = ((unsigned int)(n * 64 + quad * 16))
                         ^ (((unsigned int)rl1 & 7u) << 4);
        short8 f20 = *(const short8*)(Wb + ((size_t)4 * 64 + l) * 8);
        short8 f21 = *(const short8*)(Wb + ((size_t)5 * 64 + l) * 8);
        short8 f40 = *(const short8*)(Wb + ((size_t)8 * 64 + l) * 8);
        short8 f41 = *(const short8*)(Wb + ((size_t)9 * 64 + l) * 8);

        short8 a2A = *(const short8*)((const char*)sT2 + rl0 * 512 + bo0);
        short8 a2B = *(const short8*)((const char*)sT2 + rl1 * 512 + bo1);
        c00 = __builtin_amdgcn_mfma_f32_16x16x32_bf16(a2A, f20, c00, 0, 0, 0);
        c01 = __builtin_amdgcn_mfma_f32_16x16x32_bf16(a2A, f21, c01, 0, 0, 0);
        c10 = __builtin_amdgcn_mfma_f32_16x16x32_bf16(a2B, f20, c10, 0, 0, 0);
        c11 = __builtin_amdgcn_mfma_f32_16x16x32_bf16(a2B, f21, c11, 0, 0, 0);

        short8 a4A = *(const short8*)((const char*)sT4 + rl0 * 512 + bo0);
        short8 a4B = *(const short8*)((const char*)sT4 + rl1 * 512 + bo1);
        c00 = __builtin_amdgcn_mfma_f32_16x16x32_bf16(a4A, f40, c00, 0, 0, 0);
        c01 = __builtin_amdgcn_mfma_f32_16x16x32_bf16(a4A, f41, c01, 0, 0, 0);
        c10 = __builtin_amdgcn_mfma_f32_16x16x32_bf16(a4B, f40, c10, 0, 0, 0);
        c11 = __builtin_amdgcn_mfma_f32_16x16x32_bf16(a4B, f41, c11, 0, 0, 0);
    }

    // ---- epilogue: bias + nt store ----
    {
        float* op0 = out + ((size_t)n * M_VERT + (mb0 + m0l0)) * FILT;
        float* op1 = out + ((size_t)n * M_VERT + (mb0 + m0l1)) * FILT;
#pragma unroll
        for (int r = 0; r < 4; ++r) {
            int orow = quad * 4 + r;
            __builtin_nontemporal_store(c00[r] + b0, &op0[(size_t)orow * FILT + lrow]);
            __builtin_nontemporal_store(c01[r] + b1, &op0[(size_t)orow * FILT + 16 + lrow]);
            __builtin_nontemporal_store(c10[r] + b0, &op1[(size_t)orow * FILT + lrow]);
            __builtin_nontemporal_store(c11[r] + b1, &op1[(size_t)orow * FILT + 16 + lrow]);
        }
    }
}

// ---------------- launch ----------------

extern "C" void kernel_launch(void* const* d_in, const int* in_sizes, int n_in,
                              void* d_out, int out_size, void* d_ws, size_t ws_size,
                              hipStream_t stream) {
    const float* x    = (const float*)d_in[0];
    const float* vals = (const float*)d_in[1];
    const float* W    = (const float*)d_in[2];
    const float* bias = (const float*)d_in[3];
    const int*   rows = (const int*)d_in[4];
    const int*   cols = (const int*)d_in[5];
    float* out = (float*)d_out;

    // workspace: 4 bf16 T buffers (16 MiB each; T4 lives in LDS) + fill + ev + Wb
    const size_t TSZ = (size_t)M_VERT * ROWLEN;
    unsigned short* T0 = (unsigned short*)d_ws;
    unsigned short* T1 = T0 + TSZ;
    unsigned short* T2 = T1 + TSZ;
    unsigned short* T3 = T2 + TSZ;
    int*  fill = (int*)(T3 + TSZ);
    int2* ev   = (int2*)(fill + M_VERT);
    unsigned short* Wb = (unsigned short*)(ev + (size_t)M_VERT * EVROW);

    hipMemsetAsync(fill, 0, M_VERT * sizeof(int), stream);
    pack_kernel<<<M_VERT * 32 / 256, 256, 0, stream>>>(x, T0, rows, cols, vals,
                                                       fill, ev, W, Wb);

    // Chebyshev recurrence (bf16); T4 is produced inside the fused final kernel
    const u64* evq = (const u64*)ev;
    spmm_kernel<<<M_VERT / 4, 256, 0, stream>>>(fill, evq, T0, T0, T1, 0);
    spmm_kernel<<<M_VERT / 4, 256, 0, stream>>>(fill, evq, T1, T0, T2, 1);
    spmm_kernel<<<M_VERT / 4, 256, 0, stream>>>(fill, evq, T2, T1, T3, 1);

    // fused: T4 = 2*L*T3 - T2 (LDS-only) + overlapped epilogue GEMM
    spmm4_gemm_kernel<<<M_VERT / 64, 1024, 0, stream>>>(fill, evq, T0, T1, T2, T3,
                                                        Wb, bias, out);
}

// Round 14
// 216.344 us; speedup vs baseline: 1.0604x; 1.0604x over previous
//
#include <hip/hip_runtime.h>

#define M_VERT 32768
#define NBATCH 8
#define FIN 32
#define RANK 5
#define FILT 32
#define E_NNZ 262144
#define ROWLEN 256                    // NBATCH*FIN elements per vertex row
#define EVROW 40                      // fixed ev slots per row (P(cnt>40) ~ 1e-16), mult of 8

typedef short short8 __attribute__((ext_vector_type(8)));
typedef float f32x4 __attribute__((ext_vector_type(4)));
typedef unsigned long long u64;

__device__ __forceinline__ float bfl(unsigned int u) {           // low bf16 -> f32
    unsigned int x = u << 16; return __builtin_bit_cast(float, x);
}
__device__ __forceinline__ float bfh(unsigned int u) {           // high bf16 -> f32
    unsigned int x = u & 0xffff0000u; return __builtin_bit_cast(float, x);
}
__device__ __forceinline__ unsigned int f2bf(float f) {          // f32 -> bf16 (RNE)
    unsigned int x = __builtin_bit_cast(unsigned int, f);
    return (x + 0x7fffu + ((x >> 16) & 1u)) >> 16;
}
__device__ __forceinline__ unsigned int pk(float a, float b) {
    return f2bf(a) | (f2bf(b) << 16);
}

// ---------------- pack x -> T0 bf16 + CSR build + packw (R6/R10-proven) ----------------

__global__ void pack_kernel(const float* __restrict__ x, unsigned short* __restrict__ T0,
                            const int* __restrict__ rows, const int* __restrict__ cols,
                            const float* __restrict__ vals,
                            int* __restrict__ fill, int2* __restrict__ ev,
                            const float* __restrict__ W, unsigned short* __restrict__ Wb) {
    int tid = blockIdx.x * blockDim.x + threadIdx.x;   // M*32 threads
    int m = tid >> 5;
    int r = tid & 31;
    int n = r >> 2;
    int q = r & 3;
    const float* src = x + ((size_t)n * M_VERT + m) * FIN + q * 8;
    float4 v0 = *(const float4*)(src);
    float4 v1 = *(const float4*)(src + 4);
    uint4 u;
    u.x = pk(v0.x, v0.y); u.y = pk(v0.z, v0.w);
    u.z = pk(v1.x, v1.y); u.w = pk(v1.z, v1.w);
    *(uint4*)(T0 + (size_t)m * ROWLEN + n * FIN + q * 8) = u;

    if (tid < E_NNZ) {
        int rr = rows[tid];
        int pos = atomicAdd(&fill[rr], 1);
        if (pos < EVROW) {                       // safety clamp (never taken in practice)
            int2 p; p.x = cols[tid]; p.y = __builtin_bit_cast(int, vals[tid]);
            ev[rr * EVROW + pos] = p;
        }
    }

    if (tid < 640) {
        int lane = tid & 63;
        int kf = tid >> 6;
        int k = kf >> 1, ft = kf & 1;
        int f = ft * 16 + (lane & 15);
        int fin0 = (lane >> 4) * 8;
        unsigned short tmp[8];
#pragma unroll
        for (int j = 0; j < 8; ++j)
            tmp[j] = (unsigned short)f2bf(W[((fin0 + j) * RANK + k) * FILT + f]);
        uint4 uw;
        uw.x = (unsigned int)tmp[0] | ((unsigned int)tmp[1] << 16);
        uw.y = (unsigned int)tmp[2] | ((unsigned int)tmp[3] << 16);
        uw.z = (unsigned int)tmp[4] | ((unsigned int)tmp[5] << 16);
        uw.w = (unsigned int)tmp[6] | ((unsigned int)tmp[7] << 16);
        *(uint4*)(Wb + (size_t)tid * 8) = uw;
    }
}

// ---------------- SpMM (bf16): Tout = L*Tin  or  2*L*Tin - Tsub (R11-proven) ----------------
// One wave per vertex; uniform bounds via readfirstlane -> scalar ev loads; 64
// lanes gather the SAME row -> one coalesced 512B transaction per edge; 8
// outstanding gathers. Masked tail -> no ev memset.
// Tout store CACHED: R13 measured that it supplies ~26 MB of warm L2 lines to
// the successor's gather demand (nt-store cost +26.5 MB FETCH / +12 us in the
// consumer). Tsub nt (pure stream, never re-read on the gather path).

__global__ __launch_bounds__(256) void spmm_kernel(const int* __restrict__ cnt,
                                                   const u64* __restrict__ ev,
                                                   const unsigned short* __restrict__ Tin,
                                                   const unsigned short* __restrict__ Tsub,
                                                   unsigned short* __restrict__ Tout, int cheb) {
    int w = threadIdx.x >> 6;
    int l = threadIdx.x & 63;
    int m = blockIdx.x * 4 + w;
    unsigned int coff = (unsigned int)l * 8u;    // byte offset within 512B row
    int c = __builtin_amdgcn_readfirstlane(cnt[m]);
    if (c > EVROW) c = EVROW;                    // matches scatter clamp
    int s = m * EVROW;
    int cf = c & ~7;
    const char* tb = (const char*)Tin;
    float a0 = 0.f, a1 = 0.f, a2 = 0.f, a3 = 0.f;
    int j = 0;
    for (; j < cf; j += 8) {                     // full 8-packs (no predication)
        u64 ed[8];
#pragma unroll
        for (int i = 0; i < 8; ++i) ed[i] = ev[s + j + i];   // uniform -> scalar loads
        uint2 t[8];
#pragma unroll
        for (int i = 0; i < 8; ++i)
            t[i] = *(const uint2*)(tb + (((unsigned int)ed[i]) << 9) + coff);
#pragma unroll
        for (int i = 0; i < 8; ++i) {
            float v = __builtin_bit_cast(float, (unsigned int)(ed[i] >> 32));
            a0 += v * bfl(t[i].x); a1 += v * bfh(t[i].x);
            a2 += v * bfl(t[i].y); a3 += v * bfh(t[i].y);
        }
    }
    if (j < c) {                                 // masked tail (1..7 real edges)
        int rem = c - j;
        u64 ed[8];
#pragma unroll
        for (int i = 0; i < 8; ++i) ed[i] = ev[s + j + i];   // may read garbage pads
        unsigned int cm[8]; float vm[8];
#pragma unroll
        for (int i = 0; i < 8; ++i) {            // mask BEFORE any deref
            bool ok = i < rem;
            cm[i] = ok ? (unsigned int)ed[i] : 0u;
            vm[i] = ok ? __builtin_bit_cast(float, (unsigned int)(ed[i] >> 32)) : 0.f;
        }
        uint2 t[8];
#pragma unroll
        for (int i = 0; i < 8; ++i)
            t[i] = *(const uint2*)(tb + (cm[i] << 9) + coff);
#pragma unroll
        for (int i = 0; i < 8; ++i) {
            a0 += vm[i] * bfl(t[i].x); a1 += vm[i] * bfh(t[i].x);
            a2 += vm[i] * bfl(t[i].y); a3 += vm[i] * bfh(t[i].y);
        }
    }
    size_t moff = (size_t)m * 512 + coff;
    if (cheb) {
        u64 o = __builtin_nontemporal_load((const u64*)((const char*)Tsub + moff));
        unsigned int ox = (unsigned int)o, oy = (unsigned int)(o >> 32);
        a0 = 2.f * a0 - bfl(ox); a1 = 2.f * a1 - bfh(ox);
        a2 = 2.f * a2 - bfl(oy); a3 = 2.f * a3 - bfh(oy);
    }
    uint2 rr;
    rr.x = pk(a0, a1); rr.y = pk(a2, a3);
    *(uint2*)((char*)Tout + moff) = rr;
}

// ---------------- fused final SpMM + GEMM (overlapped, R11-proven) ----------------
// Block = 1024 threads (16 waves) owns 64 vertices.
// Phase A: wave w computes T4 rows w*4..+3 = 2*L*T3 - T2 into LDS (swizzled);
// the T2 row it reads for the recurrence is ALSO stashed into LDS (sT2) --
// phase B's k=2 then never touches global. Overlap: k in {0,1,3} gemm (A global
// loads + 6/10 MFMAs, Wb frags shared by the wave's 2 tasks) runs BEFORE
// __syncthreads -- early-finishing waves issue their A-reads while stragglers
// drain. Only k=2/k=4 (LDS) run post-barrier. Both tasks' accumulators live
// across the barrier, explicitly unrolled (static indexing).

__global__ __launch_bounds__(1024, 8) void spmm4_gemm_kernel(
        const int* __restrict__ cnt, const u64* __restrict__ ev,
        const unsigned short* __restrict__ T0, const unsigned short* __restrict__ T1,
        const unsigned short* __restrict__ T2, const unsigned short* __restrict__ T3,
        const unsigned short* __restrict__ Wb, const float* __restrict__ bias,
        float* __restrict__ out) {
    __shared__ unsigned short sT4[64 * 256];     // 32 KB, swizzled
    __shared__ unsigned short sT2[64 * 256];     // 32 KB, swizzled
    int w = threadIdx.x >> 6;                    // wave 0..15
    int l = threadIdx.x & 63;
    int mb0 = blockIdx.x * 64;
    unsigned int coff = (unsigned int)l * 8u;
    const char* tb = (const char*)T3;            // Tin = T3

    // ---- phase A: T4 rows = 2*L*T3 - T2 -> sT4; raw T2 rows -> sT2 ----
    for (int vi = 0; vi < 4; ++vi) {
        int lr = w * 4 + vi;                     // local row 0..63
        int m = mb0 + lr;
        int c = __builtin_amdgcn_readfirstlane(cnt[m]);
        if (c > EVROW) c = EVROW;
        int s = m * EVROW;
        int cf = c & ~7;
        float a0 = 0.f, a1 = 0.f, a2 = 0.f, a3 = 0.f;
        int j = 0;
        for (; j < cf; j += 8) {
            u64 ed[8];
#pragma unroll
            for (int i = 0; i < 8; ++i) ed[i] = ev[s + j + i];
            uint2 t[8];
#pragma unroll
            for (int i = 0; i < 8; ++i)
                t[i] = *(const uint2*)(tb + (((unsigned int)ed[i]) << 9) + coff);
#pragma unroll
            for (int i = 0; i < 8; ++i) {
                float v = __builtin_bit_cast(float, (unsigned int)(ed[i] >> 32));
                a0 += v * bfl(t[i].x); a1 += v * bfh(t[i].x);
                a2 += v * bfl(t[i].y); a3 += v * bfh(t[i].y);
            }
        }
        if (j < c) {
            int rem = c - j;
            u64 ed[8];
#pragma unroll
            for (int i = 0; i < 8; ++i) ed[i] = ev[s + j + i];
            unsigned int cm[8]; float vm[8];
#pragma unroll
            for (int i = 0; i < 8; ++i) {
                bool ok = i < rem;
                cm[i] = ok ? (unsigned int)ed[i] : 0u;
                vm[i] = ok ? __builtin_bit_cast(float, (unsigned int)(ed[i] >> 32)) : 0.f;
            }
            uint2 t[8];
#pragma unroll
            for (int i = 0; i < 8; ++i)
                t[i] = *(const uint2*)(tb + (cm[i] << 9) + coff);
#pragma unroll
            for (int i = 0; i < 8; ++i) {
                a0 += vm[i] * bfl(t[i].x); a1 += vm[i] * bfh(t[i].x);
                a2 += vm[i] * bfl(t[i].y); a3 += vm[i] * bfh(t[i].y);
            }
        }
        size_t moff = (size_t)(mb0 + lr) * 512 + coff;
        u64 o = *(const u64*)((const char*)T2 + moff);        // cached: reused via sT2
        unsigned int ox = (unsigned int)o, oy = (unsigned int)(o >> 32);
        unsigned int swz = coff ^ (((unsigned int)lr & 7u) << 4);
        *(u64*)((char*)sT2 + lr * 512 + swz) = o;             // stash raw T2 row
        a0 = 2.f * a0 - bfl(ox); a1 = 2.f * a1 - bfh(ox);
        a2 = 2.f * a2 - bfl(oy); a3 = 2.f * a3 - bfh(oy);
        uint2 rr;
        rr.x = pk(a0, a1); rr.y = pk(a2, a3);
        *(uint2*)((char*)sT4 + lr * 512 + swz) = rr;
    }

    // ---- phase B (early, pre-barrier): k in {0,1,3} for both tasks ----
    int lrow = l & 15;           // A's m-offset AND C's column f
    int quad = l >> 4;
    float b0 = bias[lrow];
    float b1 = bias[16 + lrow];

    // task0: tt = w      -> n = w&7, rg = w>>3        (0 or 1)
    // task1: tt = w + 16 -> same n,  rg = 2 + (w>>3)  (2 or 3)
    int n   = w & 7;
    int rg0 = w >> 3;
    int rg1 = 2 + rg0;
    int m0l0 = rg0 * 16, m0l1 = rg1 * 16;
    size_t ab0 = (size_t)(mb0 + m0l0 + lrow) * ROWLEN + quad * 8 + n * FIN;
    size_t ab1 = (size_t)(mb0 + m0l1 + lrow) * ROWLEN + quad * 8 + n * FIN;

    f32x4 c00 = {0.f, 0.f, 0.f, 0.f};   // task0, filt 0-15
    f32x4 c01 = {0.f, 0.f, 0.f, 0.f};   // task0, filt 16-31
    f32x4 c10 = {0.f, 0.f, 0.f, 0.f};   // task1, filt 0-15
    f32x4 c11 = {0.f, 0.f, 0.f, 0.f};   // task1, filt 16-31

    const unsigned short* TsG[3] = {T0, T1, T3};
    const int kgl[3] = {0, 1, 3};
#pragma unroll
    for (int ki = 0; ki < 3; ++ki) {
        int k = kgl[ki];
        short8 f0 = *(const short8*)(Wb + ((size_t)(k * 2 + 0) * 64 + l) * 8);
        short8 f1 = *(const short8*)(Wb + ((size_t)(k * 2 + 1) * 64 + l) * 8);
        short8 aA = *(const short8*)(TsG[ki] + ab0);
        short8 aB = *(const short8*)(TsG[ki] + ab1);
        c00 = __builtin_amdgcn_mfma_f32_16x16x32_bf16(aA, f0, c00, 0, 0, 0);
        c01 = __builtin_amdgcn_mfma_f32_16x16x32_bf16(aA, f1, c01, 0, 0, 0);
        c10 = __builtin_amdgcn_mfma_f32_16x16x32_bf16(aB, f0, c10, 0, 0, 0);
        c11 = __builtin_amdgcn_mfma_f32_16x16x32_bf16(aB, f1, c11, 0, 0, 0);
    }

    __syncthreads();

    // ---- phase B (late, post-barrier): k=2 (sT2) and k=4 (sT4) ----
    {
        int rl0 = m0l0 + lrow;
        int rl1 = m0l1 + lrow;
        unsigned int bo0 = ((unsigned int)(n * 64 + quad * 16))
                         ^ (((unsigned int)rl0 & 7u) << 4);
        unsigned int bo1 = ((unsigned int)(n * 64 + quad * 16))
                         ^ (((unsigned int)rl1 & 7u) << 4);
        short8 f20 = *(const short8*)(Wb + ((size_t)4 * 64 + l) * 8);
        short8 f21 = *(const short8*)(Wb + ((size_t)5 * 64 + l) * 8);
        short8 f40 = *(const short8*)(Wb + ((size_t)8 * 64 + l) * 8);
        short8 f41 = *(const short8*)(Wb + ((size_t)9 * 64 + l) * 8);

        short8 a2A = *(const short8*)((const char*)sT2 + rl0 * 512 + bo0);
        short8 a2B = *(const short8*)((const char*)sT2 + rl1 * 512 + bo1);
        c00 = __builtin_amdgcn_mfma_f32_16x16x32_bf16(a2A, f20, c00, 0, 0, 0);
        c01 = __builtin_amdgcn_mfma_f32_16x16x32_bf16(a2A, f21, c01, 0, 0, 0);
        c10 = __builtin_amdgcn_mfma_f32_16x16x32_bf16(a2B, f20, c10, 0, 0, 0);
        c11 = __builtin_amdgcn_mfma_f32_16x16x32_bf16(a2B, f21, c11, 0, 0, 0);

        short8 a4A = *(const short8*)((const char*)sT4 + rl0 * 512 + bo0);
        short8 a4B = *(const short8*)((const char*)sT4 + rl1 * 512 + bo1);
        c00 = __builtin_amdgcn_mfma_f32_16x16x32_bf16(a4A, f40, c00, 0, 0, 0);
        c01 = __builtin_amdgcn_mfma_f32_16x16x32_bf16(a4A, f41, c01, 0, 0, 0);
        c10 = __builtin_amdgcn_mfma_f32_16x16x32_bf16(a4B, f40, c10, 0, 0, 0);
        c11 = __builtin_amdgcn_mfma_f32_16x16x32_bf16(a4B, f41, c11, 0, 0, 0);
    }

    // ---- epilogue: bias + nt store ----
    {
        float* op0 = out + ((size_t)n * M_VERT + (mb0 + m0l0)) * FILT;
        float* op1 = out + ((size_t)n * M_VERT + (mb0 + m0l1)) * FILT;
#pragma unroll
        for (int r = 0; r < 4; ++r) {
            int orow = quad * 4 + r;
            __builtin_nontemporal_store(c00[r] + b0, &op0[(size_t)orow * FILT + lrow]);
            __builtin_nontemporal_store(c01[r] + b1, &op0[(size_t)orow * FILT + 16 + lrow]);
            __builtin_nontemporal_store(c10[r] + b0, &op1[(size_t)orow * FILT + lrow]);
            __builtin_nontemporal_store(c11[r] + b1, &op1[(size_t)orow * FILT + 16 + lrow]);
        }
    }
}

// ---------------- launch ----------------

extern "C" void kernel_launch(void* const* d_in, const int* in_sizes, int n_in,
                              void* d_out, int out_size, void* d_ws, size_t ws_size,
                              hipStream_t stream) {
    const float* x    = (const float*)d_in[0];
    const float* vals = (const float*)d_in[1];
    const float* W    = (const float*)d_in[2];
    const float* bias = (const float*)d_in[3];
    const int*   rows = (const int*)d_in[4];
    const int*   cols = (const int*)d_in[5];
    float* out = (float*)d_out;

    // workspace: 4 bf16 T buffers (16 MiB each; T4 lives in LDS) + fill + ev + Wb
    const size_t TSZ = (size_t)M_VERT * ROWLEN;
    unsigned short* T0 = (unsigned short*)d_ws;
    unsigned short* T1 = T0 + TSZ;
    unsigned short* T2 = T1 + TSZ;
    unsigned short* T3 = T2 + TSZ;
    int*  fill = (int*)(T3 + TSZ);
    int2* ev   = (int2*)(fill + M_VERT);
    unsigned short* Wb = (unsigned short*)(ev + (size_t)M_VERT * EVROW);

    hipMemsetAsync(fill, 0, M_VERT * sizeof(int), stream);
    pack_kernel<<<M_VERT * 32 / 256, 256, 0, stream>>>(x, T0, rows, cols, vals,
                                                       fill, ev, W, Wb);

    // Chebyshev recurrence (bf16); T4 is produced inside the fused final kernel
    const u64* evq = (const u64*)ev;
    spmm_kernel<<<M_VERT / 4, 256, 0, stream>>>(fill, evq, T0, T0, T1, 0);
    spmm_kernel<<<M_VERT / 4, 256, 0, stream>>>(fill, evq, T1, T0, T2, 1);
    spmm_kernel<<<M_VERT / 4, 256, 0, stream>>>(fill, evq, T2, T1, T3, 1);

    // fused: T4 = 2*L*T3 - T2 (LDS-only) + overlapped epilogue GEMM
    spmm4_gemm_kernel<<<M_VERT / 64, 1024, 0, stream>>>(fill, evq, T0, T1, T2, T3,
                                                        Wb, bias, out);
}